// Round 4
// baseline (1226.196 us; speedup 1.0000x reference)
//
#include <hip/hip_runtime.h>
#include <math.h>

static constexpr int TT = 1024, BB = 64, DHID = 256, NLAY = 8, OSL = 24;

typedef __attribute__((ext_vector_type(8))) short short8;   // 8 bf16
typedef __attribute__((ext_vector_type(4))) float f32x4;
typedef unsigned short u16;
typedef __attribute__((ext_vector_type(4))) unsigned short u16x4;
typedef unsigned int u32;

__device__ __forceinline__ u16 f2bf(float x) {
  u32 u = __float_as_uint(x);
  return (u16)((u + 0x7fffu + ((u >> 16) & 1u)) >> 16);   // RNE
}

__device__ __forceinline__ void gll16(const u16* g, u16* l) {
  // async global->LDS, 16B/lane; LDS dest = wave-uniform base + lane*16
  __builtin_amdgcn_global_load_lds((const __attribute__((address_space(1))) void*)g,
                                   (__attribute__((address_space(3))) void*)l, 16, 0, 0);
}

// ---------------------------------------------------------------------------
// Weight prep: conv_w [l][o][c][k] f32 -> wT [l][tap][o][c] bf16;
//              skip_w [l][o][c] f32 -> swT bf16 (same layout).
// ---------------------------------------------------------------------------
__global__ __launch_bounds__(256) void wprep(
    const float* __restrict__ cw, const float* __restrict__ sw,
    u16* __restrict__ wT, u16* __restrict__ swT)
{
  const int stride = gridDim.x * 256;
  for (int idx = blockIdx.x * 256 + threadIdx.x; idx < NLAY * 3 * 512 * 256; idx += stride) {
    const int c = idx & 255;
    const int o = (idx >> 8) & 511;
    const int lt = idx >> 17;
    const int tap = lt % 3, l = lt / 3;
    wT[idx] = f2bf(cw[((size_t)(l * 512 + o) * 256 + c) * 3 + tap]);
  }
  for (int idx = blockIdx.x * 256 + threadIdx.x; idx < NLAY * 512 * 256; idx += stride)
    swT[idx] = f2bf(sw[idx]);
}

// ---------------------------------------------------------------------------
// Up projection -> h_f32 [b][t][c] + bf16 mirror, t >= 192 only (tiles >= 3;
// layer 0 only reads t >= 254 and RMWs tiles >= 4).
// ---------------------------------------------------------------------------
__global__ __launch_bounds__(256) void up_kernel(
    const float* __restrict__ xlag, const float* __restrict__ xcov,
    const float* __restrict__ upw, const float* __restrict__ upb,
    float* __restrict__ h, u16* __restrict__ hb0)
{
  const int b  = blockIdx.y;
  const int t0 = 192 + blockIdx.x * 16;
  __shared__ float xs[16][17];
  {
    const int tl = threadIdx.x >> 4;
    const int j  = threadIdx.x & 15;
    const size_t base = ((size_t)(t0 + tl) * BB + b) * 8;
    xs[tl][j] = (j < 8) ? xlag[base + j] : xcov[base + (j - 8)];
  }
  __syncthreads();
  const int c = threadIdx.x;
  float uw[16];
#pragma unroll
  for (int j = 0; j < 16; ++j) uw[j] = upw[j * DHID + c];
  const float bias = upb[c];
#pragma unroll
  for (int tl = 0; tl < 16; ++tl) {
    float acc = bias;
#pragma unroll
    for (int j = 0; j < 16; ++j) acc = fmaf(xs[tl][j], uw[j], acc);
    const size_t idx = ((size_t)b * TT + t0 + tl) * DHID + c;
    h[idx]   = acc;
    hb0[idx] = f2bf(acc);
  }
}

// ---------------------------------------------------------------------------
// Fused layer, N=128 (batch pair), 16 waves, pipelined dbuf staging.
// LDS layouts ([part][row] 16B slots -> all ds_read_b128 conflict-free):
//   As[buf]: slot = part*512 + o        (conv: 512 rows; skip last: 512; else [part*256+o])
//   Bs[buf]: slot = part*128 + t'       (t' = batch*64 + tl)
//   gS     : slot = cpart*128 + t'      (cpart = c>>3)
// ---------------------------------------------------------------------------
__global__ __launch_bounds__(1024) void layer_fused(
    const u16* __restrict__ hbin, const u16* __restrict__ wT,
    const float* __restrict__ cb, const u16* __restrict__ swTl,
    const float* __restrict__ sb, float* __restrict__ hf,
    u16* __restrict__ hbout, float* __restrict__ skipf,
    const int dil, const int tile0)
{
  __shared__ u16 As[2][2048 * 8];   // 64 KB
  __shared__ u16 Bs[2][512 * 8];    // 16 KB
  __shared__ u16 gS[4096 * 8];      // 64 KB

  const int b0   = blockIdx.y * 2;
  const int tile = tile0 + blockIdx.x;
  const int t0   = tile * 64;
  const bool last = (tile == 15);
  const int tid = threadIdx.x;
  const int w = tid >> 6, lane = tid & 63;
  const int l16 = lane & 15, quad = lane >> 4;
  const u16* hbB = hbin + (size_t)b0 * TT * DHID;

  f32x4 acc[2][8];
  const f32x4 zero = {0.f, 0.f, 0.f, 0.f};
#pragma unroll
  for (int m = 0; m < 2; ++m)
#pragma unroll
    for (int n = 0; n < 8; ++n) acc[m][n] = zero;

  // ----- staging helpers (per-lane global src; wave-uniform LDS base) -----
  auto stageConv = [&](int buf, int tap, int kc) {
    const int sh = (2 - tap) * dil;
    const int c0 = kc * 32;
    const u16* wtap = wT + (size_t)tap * 512 * 256;
#pragma unroll
    for (int q = 0; q < 2; ++q) {
      const int s = q * 1024 + tid;
      const int p = s >> 9, o = s & 511;
      gll16(wtap + (size_t)o * 256 + c0 + p * 8, As[buf] + (size_t)(s & ~63) * 8);
    }
    if (tid < 512) {
      const int s = tid;
      const int p = s >> 7, tp = s & 127;
      gll16(hbB + ((size_t)(tp >> 6) * TT + (t0 - sh + (tp & 63))) * 256 + c0 + p * 8,
            Bs[buf] + (size_t)(s & ~63) * 8);
    }
  };
  auto stageSkip = [&](int buf, int kc) {
    const int c0 = kc * 32;
    if (!last) {
      const int s = tid;                    // [p:4][o:256]
      const int p = s >> 8, o = s & 255;
      gll16(swTl + (size_t)o * 256 + c0 + p * 8, As[buf] + (size_t)(s & ~63) * 8);
    } else {
#pragma unroll
      for (int q = 0; q < 2; ++q) {
        const int s = q * 1024 + tid;       // [p:4][o:512]
        const int p = s >> 9, o = s & 511;
        gll16(swTl + (size_t)o * 256 + c0 + p * 8, As[buf] + (size_t)(s & ~63) * 8);
      }
    }
  };

  // ---------------- phase 1: conv + gate (24 pipelined steps) ----------------
  stageConv(0, 0, 0);
  __syncthreads();
  for (int step = 0; step < 24; ++step) {
    const int ns = step + 1;
    if (ns < 24) stageConv(ns & 1, ns >> 3, ns & 7);
    else         stageSkip(0, 0);           // prefetch skip step 0 into buf 0
    const u16* A = As[step & 1];
    const u16* B = Bs[step & 1];
    const short8 af0 = *(const short8*)&A[(size_t)(quad * 512 + 16 * w + l16) * 8];
    const short8 af1 = *(const short8*)&A[(size_t)(quad * 512 + 256 + 16 * w + l16) * 8];
#pragma unroll
    for (int half = 0; half < 2; ++half) {
      short8 bf[4];
#pragma unroll
      for (int j = 0; j < 4; ++j)
        bf[j] = *(const short8*)&B[(size_t)(quad * 128 + 16 * (4 * half + j) + l16) * 8];
#pragma unroll
      for (int j = 0; j < 4; ++j) {
        const int nt = 4 * half + j;
        acc[0][nt] = __builtin_amdgcn_mfma_f32_16x16x32_bf16(af0, bf[j], acc[0][nt], 0, 0, 0);
        acc[1][nt] = __builtin_amdgcn_mfma_f32_16x16x32_bf16(af1, bf[j], acc[1][nt], 0, 0, 0);
      }
    }
    __syncthreads();
  }

  // gate epilogue -> gS (2-way writes, free)
  {
    const int cpart = 2 * w + (quad >> 1);
    const int e0 = 4 * (quad & 1);
#pragma unroll
    for (int nt = 0; nt < 8; ++nt) {
      const int tp = 16 * nt + l16;
      u16x4 pk;
#pragma unroll
      for (int r = 0; r < 4; ++r) {
        const int c = 16 * w + 4 * quad + r;
        const float f = acc[0][nt][r] + cb[c];
        const float g = acc[1][nt][r] + cb[256 + c];
        const float th = 2.f / (1.f + __expf(-2.f * f)) - 1.f;
        const float sg = 1.f / (1.f + __expf(-g));
        pk[r] = f2bf(th * sg);
      }
      *(u16x4*)&gS[((size_t)cpart * 128 + tp) * 8 + e0] = pk;
    }
  }
  __syncthreads();

  // ---------------- phase 2: skip GEMM (8 pipelined steps) ----------------
#pragma unroll
  for (int m = 0; m < 2; ++m)
#pragma unroll
    for (int n = 0; n < 8; ++n) acc[m][n] = zero;

  const int aStride = last ? 512 : 256;
  for (int s2 = 0; s2 < 8; ++s2) {
    if (s2 + 1 < 8) stageSkip((25 + s2) & 1, s2 + 1);
    const u16* A = As[(24 + s2) & 1];
    const short8 a0 = *(const short8*)&A[(size_t)(quad * aStride + 16 * w + l16) * 8];
    short8 a1 = a0;
    if (last) a1 = *(const short8*)&A[(size_t)(quad * 512 + 256 + 16 * w + l16) * 8];
#pragma unroll
    for (int half = 0; half < 2; ++half) {
      short8 bf[4];
#pragma unroll
      for (int j = 0; j < 4; ++j)
        bf[j] = *(const short8*)&gS[((size_t)(4 * s2 + quad) * 128 + 16 * (4 * half + j) + l16) * 8];
#pragma unroll
      for (int j = 0; j < 4; ++j) {
        const int nt = 4 * half + j;
        acc[0][nt] = __builtin_amdgcn_mfma_f32_16x16x32_bf16(a0, bf[j], acc[0][nt], 0, 0, 0);
        if (last)
          acc[1][nt] = __builtin_amdgcn_mfma_f32_16x16x32_bf16(a1, bf[j], acc[1][nt], 0, 0, 0);
      }
    }
    __syncthreads();
  }

  // epilogue: h residual RMW + bf16 mirror; skip-half on last tile
  {
    const int c4 = 16 * w + 4 * quad;
#pragma unroll
    for (int nt = 0; nt < 8; ++nt) {
      const int tp = 16 * nt + l16;
      const int bb = b0 + (tp >> 6);
      const int t  = t0 + (tp & 63);
      const size_t idx = ((size_t)bb * TT + t) * DHID + c4;
      f32x4 hv = *(f32x4*)&hf[idx];
      u16x4 pk;
#pragma unroll
      for (int r = 0; r < 4; ++r) {
        const float v = hv[r] + acc[0][nt][r] + sb[c4 + r];
        hv[r] = v;
        pk[r] = f2bf(v);
      }
      *(f32x4*)&hf[idx] = hv;
      *(u16x4*)&hbout[idx] = pk;
    }
    if (last) {
#pragma unroll
      for (int nt = 0; nt < 8; ++nt) {
        const int tp = 16 * nt + l16;
        const int bb = b0 + (tp >> 6);
        const int tl = tp & 63;
        const size_t idx = ((size_t)bb * 64 + tl) * DHID + c4;
        f32x4 sv = *(f32x4*)&skipf[idx];
#pragma unroll
        for (int r = 0; r < 4; ++r)
          sv[r] += acc[1][nt][r] + sb[256 + c4 + r];
        *(f32x4*)&skipf[idx] = sv;
      }
    }
  }
}

// ---------------------------------------------------------------------------
// Head over last OSL timesteps; skipf layout [b][64t][256c].
// ---------------------------------------------------------------------------
__global__ __launch_bounds__(256) void head_kernel(
    const float* __restrict__ skipf,
    const float* __restrict__ fcw, const float* __restrict__ fcb,
    const float* __restrict__ locw, const float* __restrict__ locb,
    const float* __restrict__ scw, const float* __restrict__ scb,
    float* __restrict__ out)
{
  const int tt = blockIdx.x;
  const int b  = blockIdx.y;
  const int tl = 40 + tt;
  const int c  = threadIdx.x;
  __shared__ float xs[DHID];
  xs[c] = skipf[((size_t)b * 64 + tl) * DHID + c];
  __syncthreads();
  float acc = fcb[c];
#pragma unroll 8
  for (int j = 0; j < DHID; ++j) acc = fmaf(xs[j], fcw[j * DHID + c], acc);
  const float ff = fmaxf(acc, 0.f);
  float pl = ff * locw[c];
  float ps = ff * scw[c];
#pragma unroll
  for (int off = 32; off > 0; off >>= 1) {
    pl += __shfl_down(pl, off);
    ps += __shfl_down(ps, off);
  }
  __shared__ float rl[4], rs[4];
  const int wid = threadIdx.x >> 6, lane = threadIdx.x & 63;
  if (lane == 0) { rl[wid] = pl; rs[wid] = ps; }
  __syncthreads();
  if (threadIdx.x == 0) {
    const float loc = rl[0] + rl[1] + rl[2] + rl[3] + locb[0];
    const float x   = rs[0] + rs[1] + rs[2] + rs[3] + scb[0];
    const float sp  = (x > 0.f) ? (x + log1pf(expf(-x))) : log1pf(expf(x));
    out[2 + tt * BB + b]            = loc;
    out[2 + OSL * BB + tt * BB + b] = sp + 1e-6f;
  }
}

__global__ __launch_bounds__(256) void loss_kernel(
    const float* __restrict__ y, float* __restrict__ out)
{
  float s = 0.f;
  for (int i = threadIdx.x; i < OSL * BB; i += 256) {
    const int tt = i >> 6, b = i & 63;
    const float loc = out[2 + i];
    const float sc  = out[2 + OSL * BB + i];
    const float yt  = y[(size_t)(TT - OSL + tt) * BB + b];
    const float z   = (yt - loc) / sc;
    s += -0.5f * z * z - logf(sc) - 0.9189385332046727f;
  }
#pragma unroll
  for (int off = 32; off > 0; off >>= 1) s += __shfl_down(s, off);
  __shared__ float r[4];
  if ((threadIdx.x & 63) == 0) r[threadIdx.x >> 6] = s;
  __syncthreads();
  if (threadIdx.x == 0) {
    const float loss = -(r[0] + r[1] + r[2] + r[3]) / (float)(OSL * BB);
    out[0] = loss;
    out[1] = loss;
  }
}

// ---------------------------------------------------------------------------
extern "C" void kernel_launch(void* const* d_in, const int* in_sizes, int n_in,
                              void* d_out, int out_size, void* d_ws, size_t ws_size,
                              hipStream_t stream) {
  (void)in_sizes; (void)n_in; (void)out_size; (void)ws_size;
  const float* X_cov  = (const float*)d_in[1];
  const float* X_lag  = (const float*)d_in[2];
  const float* y      = (const float*)d_in[3];
  const float* up_w   = (const float*)d_in[5];
  const float* up_b   = (const float*)d_in[6];
  const float* conv_w = (const float*)d_in[7];
  const float* conv_b = (const float*)d_in[8];
  const float* skip_w = (const float*)d_in[9];
  const float* skip_b = (const float*)d_in[10];
  const float* fc_w   = (const float*)d_in[11];
  const float* fc_b   = (const float*)d_in[12];
  const float* loc_w  = (const float*)d_in[13];
  const float* loc_b  = (const float*)d_in[14];
  const float* sc_w   = (const float*)d_in[15];
  const float* sc_b   = (const float*)d_in[16];

  // workspace layout (bytes), total 147MB
  float* hf    = (float*)d_ws;                           // 64MB  [b][t][c] f32
  u16*   hb0   = (u16*)  ((char*)d_ws + 67108864);       // 32MB  bf16 ping
  u16*   hb1   = (u16*)  ((char*)d_ws + 100663296);      // 32MB  bf16 pong
  float* skipf = (float*)((char*)d_ws + 134217728);      // 4MB   [b][64][256]
  u16*   wT    = (u16*)  ((char*)d_ws + 138412032);      // 6MB
  u16*   swT   = (u16*)  ((char*)d_ws + 144703488);      // 2MB

  wprep<<<2048, 256, 0, stream>>>(conv_w, skip_w, wT, swT);
  hipMemsetAsync(skipf, 0, (size_t)BB * 64 * DHID * sizeof(float), stream);
  up_kernel<<<dim3(52, BB), 256, 0, stream>>>(X_lag, X_cov, up_w, up_b, hf, hb0);

  // minimal t-tiles per layer (receptive-field recurrence; halo reads of layer
  // i stay within tiles layer i-1 wrote to the pong buffer)
  static const int Ptab[NLAY] = {4, 5, 6, 7, 8, 9, 11, 15};
  u16* hin = hb0;
  u16* hout = hb1;
  for (int i = 0; i < NLAY; ++i) {
    const int ntiles = 16 - Ptab[i];
    layer_fused<<<dim3(ntiles, BB / 2), 1024, 0, stream>>>(
        hin, wT + (size_t)i * 3 * 512 * 256, conv_b + i * 512,
        swT + (size_t)i * 512 * 256, skip_b + i * 512,
        hf, hout, skipf, 1 << i, Ptab[i]);
    u16* tmp = hin; hin = hout; hout = tmp;
  }

  head_kernel<<<dim3(OSL, BB), 256, 0, stream>>>(
      skipf, fc_w, fc_b, loc_w, loc_b, sc_w, sc_b, (float*)d_out);
  loss_kernel<<<1, 256, 0, stream>>>(y, (float*)d_out);
}

// Round 5
// 665.829 us; speedup vs baseline: 1.8416x; 1.8416x over previous
//
#include <hip/hip_runtime.h>
#include <math.h>

static constexpr int TT = 1024, BB = 64, DHID = 256, NLAY = 8, OSL = 24;
static constexpr int T0H = 192, THN = 832;   // h panels cover t in [192,1024)
static constexpr int T0G = 256, TGN = 768;   // gated panels cover t in [256,1024)

typedef __attribute__((ext_vector_type(8))) short short8;   // 8 bf16
typedef __attribute__((ext_vector_type(4))) float f32x4;
typedef unsigned short u16;
typedef __attribute__((ext_vector_type(4))) unsigned short u16x4;
typedef unsigned int u32;

__device__ __forceinline__ u16 f2bf(float x) {
  u32 u = __float_as_uint(x);
  return (u16)((u + 0x7fffu + ((u >> 16) & 1u)) >> 16);   // RNE
}
__device__ __forceinline__ float bf2f(u16 v) {
  return __uint_as_float((u32)v << 16);
}
__device__ __forceinline__ void gll16(const u16* g, u16* l) {
  __builtin_amdgcn_global_load_lds((const __attribute__((address_space(1))) void*)g,
                                   (__attribute__((address_space(3))) void*)l, 16, 0, 0);
}

// ---------------------------------------------------------------------------
// Weight prep into k-panelized, staging-order layouts (lane-contiguous 16B):
//  wP  [l][tap][kc][cs][p][row 256][8]   row<128: f (o=cs*128+row), else g(+256)
//  swH [l][kc][p][o 256][8]              h-half of skip_w
//  swG [l*8+kc][p][o 256][8]             g-half (K-stacked for final GEMM)
// ---------------------------------------------------------------------------
__global__ __launch_bounds__(256) void wprep(
    const float* __restrict__ cw, const float* __restrict__ sw,
    u16* __restrict__ wP, u16* __restrict__ swH, u16* __restrict__ swG)
{
  const int stride = gridDim.x * 256;
  for (int i = blockIdx.x * 256 + threadIdx.x; i < NLAY * 3 * 8 * 2 * 4 * 2048; i += stride) {
    const int e = i & 7, row = (i >> 3) & 255;
    int q = i >> 11;
    const int p = q & 3; q >>= 2;
    const int cs = q & 1; q >>= 1;
    const int kc = q & 7; q >>= 3;
    const int tap = q % 3, l = q / 3;
    const int o = (row < 128) ? (cs * 128 + row) : (256 + cs * 128 + (row - 128));
    const int c = kc * 32 + p * 8 + e;
    wP[i] = f2bf(cw[((size_t)(l * 512 + o) * 256 + c) * 3 + tap]);
  }
  for (int i = blockIdx.x * 256 + threadIdx.x; i < NLAY * 8 * 4 * 2048; i += stride) {
    const int e = i & 7, o = (i >> 3) & 255, p = (i >> 11) & 3, kc = (i >> 13) & 7, l = i >> 16;
    const int c = kc * 32 + p * 8 + e;
    swH[i] = f2bf(sw[(size_t)(l * 512 + o) * 256 + c]);
    swG[i] = f2bf(sw[(size_t)(l * 512 + 256 + o) * 256 + c]);
  }
}

// ---------------------------------------------------------------------------
// Up projection -> h bf16 panels [b][cpart][t-192][8], t in [192,1024).
// ---------------------------------------------------------------------------
__global__ __launch_bounds__(256) void up_kernel(
    const float* __restrict__ xlag, const float* __restrict__ xcov,
    const float* __restrict__ upw, const float* __restrict__ upb,
    u16* __restrict__ hb0)
{
  const int b  = blockIdx.y;
  const int t0 = T0H + blockIdx.x * 16;
  __shared__ float xs[16][17];
  {
    const int tl = threadIdx.x >> 4;
    const int j  = threadIdx.x & 15;
    const size_t base = ((size_t)(t0 + tl) * BB + b) * 8;
    xs[tl][j] = (j < 8) ? xlag[base + j] : xcov[base + (j - 8)];
  }
  __syncthreads();
  const int c = threadIdx.x;
  float uw[16];
#pragma unroll
  for (int j = 0; j < 16; ++j) uw[j] = upw[j * DHID + c];
  const float bias = upb[c];
#pragma unroll
  for (int tl = 0; tl < 16; ++tl) {
    float acc = bias;
#pragma unroll
    for (int j = 0; j < 16; ++j) acc = fmaf(xs[tl][j], uw[j], acc);
    hb0[(((size_t)b * 32 + (c >> 3)) * THN + (t0 + tl - T0H)) * 8 + (c & 7)] = f2bf(acc);
  }
}

// ---------------------------------------------------------------------------
// Conv+gate: block = M 256 (f128|g128, half cs) x N 256 (4 batches, one tile).
// 16 waves as 4Mx4N; wave owns f-rows mw*32..+31 AND g-rows 128+mw*32..+31
// -> in-register gating. Dbuf staged A(16K)+B(16K), all gll16 lane-contiguous.
// ---------------------------------------------------------------------------
__global__ __launch_bounds__(1024) void conv_gate(
    const u16* __restrict__ hbin, const u16* __restrict__ wPl,
    const float* __restrict__ cb, u16* __restrict__ gbuf,
    u16* __restrict__ g15l, const int dil, const int tile0)
{
  __shared__ u16 AB[2][16384];   // per buf: A slots 0..1023, B slots 1024..2047
  const int tid = threadIdx.x, w = tid >> 6, lane = tid & 63;
  const int l16 = lane & 15, quad = lane >> 4;
  const int mw = w & 3, nw = w >> 2;
  const int tile = tile0 + (int)(blockIdx.x >> 4);
  const int b0 = (blockIdx.x & 15) * 4;
  const int cs = blockIdx.y;
  const int t0 = tile * 64;

  f32x4 acc[4][4];
  const f32x4 zero = {0.f, 0.f, 0.f, 0.f};
#pragma unroll
  for (int m = 0; m < 4; ++m)
#pragma unroll
    for (int j = 0; j < 4; ++j) acc[m][j] = zero;

  const int ctb = tid >> 8, pb = (tid >> 6) & 3, tlb = tid & 63;   // B-stage decomp

  auto stage = [&](int buf, int tap, int kc) {
    // A: 1024 slots, lane-contiguous panel read
    gll16(wPl + (size_t)(((tap * 8 + kc) * 2 + cs)) * 8192 + tid * 8,
          &AB[buf][(tid & ~63) * 8]);
    // B: 1024 slots = 4 ct x 4 p x 64 t, contiguous within each wave
    const int sh = (2 - tap) * dil;
    gll16(hbin + (((size_t)(b0 + ctb) * 32 + kc * 4 + pb) * THN + (t0 - sh - T0H + tlb)) * 8,
          &AB[buf][8192 + (tid & ~63) * 8]);
  };

  stage(0, 0, 0);
  __syncthreads();
  for (int step = 0; step < 24; ++step) {
    const int ns = step + 1;
    if (ns < 24) stage(ns & 1, ns >> 3, ns & 7);
    const u16* A = AB[step & 1];
    const u16* B = AB[step & 1] + 8192;
    short8 bfr[4];
#pragma unroll
    for (int j = 0; j < 4; ++j)
      bfr[j] = *(const short8*)&B[(nw * 256 + quad * 64 + 16 * j + l16) * 8];
#pragma unroll
    for (int m = 0; m < 4; ++m) {
      const int rowbase = (m < 2) ? (mw * 32 + 16 * m) : (128 + mw * 32 + 16 * (m - 2));
      const short8 a = *(const short8*)&A[(quad * 256 + rowbase + l16) * 8];
#pragma unroll
      for (int j = 0; j < 4; ++j)
        acc[m][j] = __builtin_amdgcn_mfma_f32_16x16x32_bf16(a, bfr[j], acc[m][j], 0, 0, 0);
    }
    __syncthreads();
  }

  // gate in-register, transpose through LDS, coalesced global store
  u16* gT = (u16*)AB;   // [ct 4][cpl 16][tl 64][8]
#pragma unroll
  for (int m = 0; m < 2; ++m) {
    const int c4 = mw * 32 + 16 * m + quad * 4;              // local f row base
    const int cpl = c4 >> 3;
#pragma unroll
    for (int j = 0; j < 4; ++j) {
      const int tl = 16 * j + l16;
      u16x4 pk;
#pragma unroll
      for (int r = 0; r < 4; ++r) {
        const float f = acc[m][j][r]     + cb[cs * 128 + c4 + r];
        const float g = acc[m + 2][j][r] + cb[256 + cs * 128 + c4 + r];
        const float th = 2.f / (1.f + __expf(-2.f * f)) - 1.f;
        const float sg = 1.f / (1.f + __expf(-g));
        pk[r] = f2bf(th * sg);
      }
      *(u16x4*)&gT[((nw * 16 + cpl) * 64 + tl) * 8 + (quad & 1) * 4] = pk;
    }
  }
  __syncthreads();
#pragma unroll
  for (int k = 0; k < 4; ++k) {
    const int slot = k * 1024 + tid;
    const int ct = slot >> 10, cpl = (slot >> 6) & 15, tl = slot & 63;
    const short8 v = *(const short8*)&gT[slot * 8];
    const int b = b0 + ct, cpg = cs * 16 + cpl;
    *(short8*)&gbuf[(((size_t)b * 32 + cpg) * TGN + (t0 + tl - T0G)) * 8] = v;
    if (tile == 15)
      *(short8*)&g15l[(((size_t)b * 32 + cpg) * 64 + tl) * 8] = v;
  }
}

// ---------------------------------------------------------------------------
// Skip h-half GEMM + residual: M 256 x N 256 x K 256; h_new = h_old + out + b.
// Epilogue: 4 ct-rounds of LDS f32 transpose -> coalesced bf16 panel store.
// ---------------------------------------------------------------------------
__global__ __launch_bounds__(1024) void skip_h(
    const u16* __restrict__ gbuf, const u16* __restrict__ swHl,
    const float* __restrict__ sb, const u16* __restrict__ hbin,
    u16* __restrict__ hbout, const int tile0)
{
  __shared__ u16 AB[2][16384];
  const int tid = threadIdx.x, w = tid >> 6, lane = tid & 63;
  const int l16 = lane & 15, quad = lane >> 4;
  const int mw = w & 3, nw = w >> 2;
  const int tile = tile0 + (int)(blockIdx.x >> 4);
  const int b0 = (blockIdx.x & 15) * 4;
  const int t0 = tile * 64;

  f32x4 acc[4][4];
  const f32x4 zero = {0.f, 0.f, 0.f, 0.f};
#pragma unroll
  for (int m = 0; m < 4; ++m)
#pragma unroll
    for (int j = 0; j < 4; ++j) acc[m][j] = zero;

  const int ctb = tid >> 8, pb = (tid >> 6) & 3, tlb = tid & 63;

  auto stage = [&](int buf, int kc) {
    gll16(swHl + (size_t)kc * 8192 + tid * 8, &AB[buf][(tid & ~63) * 8]);
    gll16(gbuf + (((size_t)(b0 + ctb) * 32 + kc * 4 + pb) * TGN + (t0 - T0G + tlb)) * 8,
          &AB[buf][8192 + (tid & ~63) * 8]);
  };

  stage(0, 0);
  __syncthreads();
  for (int step = 0; step < 8; ++step) {
    if (step + 1 < 8) stage((step + 1) & 1, step + 1);
    const u16* A = AB[step & 1];
    const u16* B = AB[step & 1] + 8192;
    short8 bfr[4];
#pragma unroll
    for (int j = 0; j < 4; ++j)
      bfr[j] = *(const short8*)&B[(nw * 256 + quad * 64 + 16 * j + l16) * 8];
#pragma unroll
    for (int m = 0; m < 4; ++m) {
      const short8 a = *(const short8*)&A[(quad * 256 + mw * 64 + 16 * m + l16) * 8];
#pragma unroll
      for (int j = 0; j < 4; ++j)
        acc[m][j] = __builtin_amdgcn_mfma_f32_16x16x32_bf16(a, bfr[j], acc[m][j], 0, 0, 0);
    }
    __syncthreads();
  }

  // per-ct rounds: f32 transpose in LDS, then h bf16 RMW with coalesced I/O
  float* fT = (float*)AB;   // [cpl 32][tl 64][8]
  for (int ctr = 0; ctr < 4; ++ctr) {
    __syncthreads();
    if (nw == ctr) {
#pragma unroll
      for (int m = 0; m < 4; ++m) {
        const int c4 = mw * 64 + 16 * m + quad * 4;
#pragma unroll
        for (int j = 0; j < 4; ++j) {
          const int tl = 16 * j + l16;
          f32x4 v;
#pragma unroll
          for (int r = 0; r < 4; ++r) v[r] = acc[m][j][r] + sb[c4 + r];
          *(f32x4*)&fT[((c4 >> 3) * 64 + tl) * 8 + (quad & 1) * 4] = v;
        }
      }
    }
    __syncthreads();
    const int b = b0 + ctr;
#pragma unroll
    for (int k = 0; k < 2; ++k) {
      const int slot = k * 1024 + tid;        // [cpl 32][tl 64]
      const int cpl = slot >> 6, tl = slot & 63;
      const size_t idx = (((size_t)b * 32 + cpl) * THN + (t0 - T0H + tl)) * 8;
      const short8 hv = *(const short8*)&hbin[idx];
      short8 ov;
#pragma unroll
      for (int e = 0; e < 8; ++e)
        ov[e] = (short)f2bf(bf2f((u16)hv[e]) + fT[slot * 8 + e]);
      *(short8*)&hbout[idx] = ov;
    }
  }
}

// ---------------------------------------------------------------------------
// Final skip g-half: out[b][c][t] = sum over l,c' swG @ g15, K = 8*256 = 2048.
// Grid 64 (one batch each), 16 waves: wave w = rows w*16..+15, N=64.
// ---------------------------------------------------------------------------
__global__ __launch_bounds__(1024) void skip_g_final(
    const u16* __restrict__ g15, const u16* __restrict__ swG,
    float* __restrict__ skipf)
{
  __shared__ u16 AB[2][10240];   // A 1024 slots + B 256 slots per buf
  const int tid = threadIdx.x, w = tid >> 6, lane = tid & 63;
  const int l16 = lane & 15, quad = lane >> 4;
  const int b = blockIdx.x;

  f32x4 acc[4];
  const f32x4 zero = {0.f, 0.f, 0.f, 0.f};
#pragma unroll
  for (int j = 0; j < 4; ++j) acc[j] = zero;

  auto stage = [&](int buf, int ks) {   // ks = l*8+kc
    gll16(swG + (size_t)ks * 8192 + tid * 8, &AB[buf][(tid & ~63) * 8]);
    if (tid < 256) {
      const int p = tid >> 6, tl = tid & 63;
      const int l = ks >> 3, kc = ks & 7;
      gll16(g15 + ((((size_t)l * 64 + b) * 32 + kc * 4 + p) * 64 + tl) * 8,
            &AB[buf][8192 + (tid & ~63) * 8]);
    }
  };

  stage(0, 0);
  __syncthreads();
  for (int step = 0; step < 64; ++step) {
    if (step + 1 < 64) stage((step + 1) & 1, step + 1);
    const u16* A = AB[step & 1];
    const u16* B = AB[step & 1] + 8192;
    const short8 a = *(const short8*)&A[(quad * 256 + w * 16 + l16) * 8];
#pragma unroll
    for (int j = 0; j < 4; ++j) {
      const short8 bf = *(const short8*)&B[(quad * 64 + 16 * j + l16) * 8];
      acc[j] = __builtin_amdgcn_mfma_f32_16x16x32_bf16(a, bf, acc[j], 0, 0, 0);
    }
    __syncthreads();
  }
#pragma unroll
  for (int j = 0; j < 4; ++j)
#pragma unroll
    for (int r = 0; r < 4; ++r) {
      const int c = w * 16 + quad * 4 + r;
      skipf[((size_t)b * 256 + c) * 64 + 16 * j + l16] = acc[j][r];
    }
}

// ---------------------------------------------------------------------------
// Head: skipf [b][c][64]; adds sum of per-layer g-bias; fc+loc+scale.
// ---------------------------------------------------------------------------
__global__ __launch_bounds__(256) void head_kernel(
    const float* __restrict__ skipf, const float* __restrict__ skip_b,
    const float* __restrict__ fcw, const float* __restrict__ fcb,
    const float* __restrict__ locw, const float* __restrict__ locb,
    const float* __restrict__ scw, const float* __restrict__ scb,
    float* __restrict__ out)
{
  const int tt = blockIdx.x;
  const int b  = blockIdx.y;
  const int tl = 40 + tt;
  const int c  = threadIdx.x;
  __shared__ float xs[DHID];
  float sbg = 0.f;
#pragma unroll
  for (int l = 0; l < NLAY; ++l) sbg += skip_b[l * 512 + 256 + c];
  xs[c] = skipf[((size_t)b * 256 + c) * 64 + tl] + sbg;
  __syncthreads();
  float acc = fcb[c];
#pragma unroll 8
  for (int j = 0; j < DHID; ++j) acc = fmaf(xs[j], fcw[j * DHID + c], acc);
  const float ff = fmaxf(acc, 0.f);
  float pl = ff * locw[c];
  float ps = ff * scw[c];
#pragma unroll
  for (int off = 32; off > 0; off >>= 1) {
    pl += __shfl_down(pl, off);
    ps += __shfl_down(ps, off);
  }
  __shared__ float rl[4], rs[4];
  const int wid = threadIdx.x >> 6, lane = threadIdx.x & 63;
  if (lane == 0) { rl[wid] = pl; rs[wid] = ps; }
  __syncthreads();
  if (threadIdx.x == 0) {
    const float loc = rl[0] + rl[1] + rl[2] + rl[3] + locb[0];
    const float x   = rs[0] + rs[1] + rs[2] + rs[3] + scb[0];
    const float sp  = (x > 0.f) ? (x + log1pf(expf(-x))) : log1pf(expf(x));
    out[2 + tt * BB + b]            = loc;
    out[2 + OSL * BB + tt * BB + b] = sp + 1e-6f;
  }
}

__global__ __launch_bounds__(256) void loss_kernel(
    const float* __restrict__ y, float* __restrict__ out)
{
  float s = 0.f;
  for (int i = threadIdx.x; i < OSL * BB; i += 256) {
    const int tt = i >> 6, b = i & 63;
    const float loc = out[2 + i];
    const float sc  = out[2 + OSL * BB + i];
    const float yt  = y[(size_t)(TT - OSL + tt) * BB + b];
    const float z   = (yt - loc) / sc;
    s += -0.5f * z * z - logf(sc) - 0.9189385332046727f;
  }
#pragma unroll
  for (int off = 32; off > 0; off >>= 1) s += __shfl_down(s, off);
  __shared__ float r[4];
  if ((threadIdx.x & 63) == 0) r[threadIdx.x >> 6] = s;
  __syncthreads();
  if (threadIdx.x == 0) {
    const float loss = -(r[0] + r[1] + r[2] + r[3]) / (float)(OSL * BB);
    out[0] = loss;
    out[1] = loss;
  }
}

// ---------------------------------------------------------------------------
extern "C" void kernel_launch(void* const* d_in, const int* in_sizes, int n_in,
                              void* d_out, int out_size, void* d_ws, size_t ws_size,
                              hipStream_t stream) {
  (void)in_sizes; (void)n_in; (void)out_size; (void)ws_size;
  const float* X_cov  = (const float*)d_in[1];
  const float* X_lag  = (const float*)d_in[2];
  const float* y      = (const float*)d_in[3];
  const float* up_w   = (const float*)d_in[5];
  const float* up_b   = (const float*)d_in[6];
  const float* conv_w = (const float*)d_in[7];
  const float* conv_b = (const float*)d_in[8];
  const float* skip_w = (const float*)d_in[9];
  const float* skip_b = (const float*)d_in[10];
  const float* fc_w   = (const float*)d_in[11];
  const float* fc_b   = (const float*)d_in[12];
  const float* loc_w  = (const float*)d_in[13];
  const float* loc_b  = (const float*)d_in[14];
  const float* sc_w   = (const float*)d_in[15];
  const float* sc_b   = (const float*)d_in[16];

  // workspace layout (bytes), total ~109 MB
  char* wsb = (char*)d_ws;
  u16*   hb0   = (u16*)(wsb + 0);            // 27,262,976  [b][32][832][8]
  u16*   hb1   = (u16*)(wsb + 27262976);     // 27,262,976
  u16*   gbuf  = (u16*)(wsb + 54525952);     // 25,165,824  [b][32][768][8]
  u16*   g15   = (u16*)(wsb + 79691776);     // 16,777,216  [l][b][32][64][8]
  u16*   wP    = (u16*)(wsb + 96468992);     //  6,291,456
  u16*   swH   = (u16*)(wsb + 102760448);    //  1,048,576
  u16*   swG   = (u16*)(wsb + 103809024);    //  1,048,576
  float* skipf = (float*)(wsb + 104857600);  //  4,194,304  [b][256][64]

  wprep<<<1024, 256, 0, stream>>>(conv_w, skip_w, wP, swH, swG);
  up_kernel<<<dim3(52, BB), 256, 0, stream>>>(X_lag, X_cov, up_w, up_b, hb0);

  // minimal t-tiles per layer (receptive-field recurrence, verified tight at
  // i=5,6,7: 64*P(i) - 2^(i+1) >= 64*P(i-1))
  static const int Ptab[NLAY] = {4, 5, 6, 7, 8, 9, 11, 15};
  u16* hin = hb0;
  u16* hout = hb1;
  for (int i = 0; i < NLAY; ++i) {
    const int ntiles = 16 - Ptab[i];
    conv_gate<<<dim3(ntiles * 16, 2), 1024, 0, stream>>>(
        hin, wP + (size_t)i * 393216, conv_b + i * 512, gbuf,
        g15 + (size_t)i * 1048576, 1 << i, Ptab[i]);
    skip_h<<<dim3(ntiles * 16), 1024, 0, stream>>>(
        gbuf, swH + (size_t)i * 65536, skip_b + i * 512, hin, hout, Ptab[i]);
    u16* tmp = hin; hin = hout; hout = tmp;
  }

  skip_g_final<<<dim3(64), 1024, 0, stream>>>(g15, swG, skipf);
  head_kernel<<<dim3(OSL, BB), 256, 0, stream>>>(
      skipf, skip_b, fc_w, fc_b, loc_w, loc_b, sc_w, sc_b, (float*)d_out);
  loss_kernel<<<1, 256, 0, stream>>>(y, (float*)d_out);
}